// Round 5
// baseline (1188.189 us; speedup 1.0000x reference)
//
#include <hip/hip_runtime.h>
#include <hip/hip_bf16.h>
#include <stdint.h>

typedef __attribute__((ext_vector_type(8))) short short8;
typedef __attribute__((ext_vector_type(4))) float f32x4;

#if defined(__has_builtin)
#if __has_builtin(__builtin_amdgcn_cvt_pk_bf16_f32)
#define HAVE_PK_BF16 1
#endif
#endif

__device__ __forceinline__ float b2f(ushort u) {
  union { uint32_t i; float f; } v; v.i = ((uint32_t)u) << 16; return v.f;
}
__device__ __forceinline__ ushort f2b_sw(float f) {
  union { float f; uint32_t i; } v; v.f = f;
  uint32_t x = v.i;
  uint32_t r = x + 0x7FFFu + ((x >> 16) & 1u);
  return (ushort)(r >> 16);
}
// packed f32x2 -> bf16x2 (HW v_cvt_pk_bf16_f32 when available; RNE either way)
__device__ __forceinline__ uint pk2(float lo, float hi) {
#ifdef HAVE_PK_BF16
  auto r = __builtin_amdgcn_cvt_pk_bf16_f32(lo, hi);
  union { decltype(r) v; uint u; } c; c.v = r; return c.u;
#else
  return (uint)f2b_sw(lo) | ((uint)f2b_sw(hi) << 16);
#endif
}
__device__ __forceinline__ ushort f2b(float f) {
#ifdef HAVE_PK_BF16
  return (ushort)(pk2(f, 0.f) & 0xFFFFu);
#else
  return f2b_sw(f);
#endif
}
__device__ __forceinline__ float lo2f(uint v) { return b2f((ushort)(v & 0xFFFFu)); }
__device__ __forceinline__ float hi2f(uint v) { return b2f((ushort)(v >> 16)); }

__device__ __forceinline__ uint4 pkf8(float4 a, float4 b) {
  uint4 o;
  o.x = pk2(a.x, a.y); o.y = pk2(a.z, a.w);
  o.z = pk2(b.x, b.y); o.w = pk2(b.z, b.w);
  return o;
}
__device__ __forceinline__ uint sub2(uint a, uint b) {
  return pk2(lo2f(a) - lo2f(b), hi2f(a) - hi2f(b));
}
__device__ __forceinline__ uint4 sub8(uint4 a, uint4 b) {
  uint4 o; o.x = sub2(a.x,b.x); o.y = sub2(a.y,b.y); o.z = sub2(a.z,b.z); o.w = sub2(a.w,b.w); return o;
}
// relu(a + b) on packed bf16 pairs, f32 arithmetic
__device__ __forceinline__ uint addrelu2(uint a, uint b) {
  return pk2(fmaxf(lo2f(a) + lo2f(b), 0.f), fmaxf(hi2f(a) + hi2f(b), 0.f));
}
__device__ __forceinline__ uint4 addrelu8(uint4 a, uint4 b) {
  uint4 o; o.x = addrelu2(a.x,b.x); o.y = addrelu2(a.y,b.y);
  o.z = addrelu2(a.z,b.z); o.w = addrelu2(a.w,b.w); return o;
}
__device__ __forceinline__ uint relu2(uint v) {
  uint lo = (v & 0x8000u) ? 0u : (v & 0xFFFFu);
  uint hi = (v & 0x80000000u) ? 0u : (v & 0xFFFF0000u);
  return lo | hi;
}
__device__ __forceinline__ uint4 relu8(uint4 v) {
  uint4 o; o.x = relu2(v.x); o.y = relu2(v.y); o.z = relu2(v.z); o.w = relu2(v.w); return o;
}

__global__ void zero_ints(int* __restrict__ p, int n) {
  int i = blockIdx.x * blockDim.x + threadIdx.x;
  if (i < n) p[i] = 0;
}

// ---------- weight prep: transposes + bf16 + fused conv|edge weight + fused bias ----------
__global__ void prep_weights(const float* __restrict__ wn, const float* __restrict__ we,
                             const float* __restrict__ cw, const float* __restrict__ ow,
                             const float* __restrict__ cb, const float* __restrict__ be,
                             ushort* __restrict__ wnT, ushort* __restrict__ weT,
                             ushort* __restrict__ cweT, ushort* __restrict__ owT,
                             float* __restrict__ cbe) {
  int i = blockIdx.x * blockDim.x + threadIdx.x;
  if (i < 16384) {
    int n = i >> 7, k = i & 127; wnT[n*128+k] = f2b(wn[k*128+n]);
  } else if (i < 32768) {
    int j = i - 16384; int n = j >> 7, k = j & 127; owT[n*128+k] = f2b(ow[k*128+n]);
  } else if (i < 53248) {
    int j = i - 32768;           // 128*160 = 20480 entries
    int n = j / 160, k = j % 160;
    cweT[n*160+k] = (k < 128) ? f2b(cw[k*128+n]) : f2b(we[(k-128)*128+n]);
  } else if (i < 57344) {
    int j = i - 53248; int n = j >> 5, k = j & 31; weT[n*32+k] = f2b(we[k*128+n]);
  } else if (i < 57472) {
    int j = i - 57344; cbe[j] = cb[j] + be[j];
  }
}

// ---------- CSR build ----------
__global__ void count_dst(const int* __restrict__ dst, int* __restrict__ counts, int E) {
  for (int i = blockIdx.x * blockDim.x + threadIdx.x; i < E; i += gridDim.x * blockDim.x)
    atomicAdd(&counts[dst[i]], 1);
}
__global__ __launch_bounds__(1024) void scan_offsets(
    const int* __restrict__ counts, int* __restrict__ off,
    int* __restrict__ cursor, int N) {
  __shared__ int part[1024];
  int t = threadIdx.x;
  int chunk = (N + 1023) >> 10;
  int lo = t * chunk, hi = min(lo + chunk, N);
  int s = 0;
  for (int i = lo; i < hi; ++i) s += counts[i];
  part[t] = s;
  __syncthreads();
  for (int d = 1; d < 1024; d <<= 1) {
    int v = (t >= d) ? part[t - d] : 0;
    __syncthreads();
    part[t] += v;
    __syncthreads();
  }
  int run = (t > 0) ? part[t - 1] : 0;
  for (int i = lo; i < hi; ++i) {
    off[i] = run; cursor[i] = run; run += counts[i];
  }
  if (t == 1023) off[N] = part[1023];
}
__global__ void fill_csr(const int* __restrict__ dst, int* __restrict__ cursor,
                         int* __restrict__ eids, int E) {
  for (int i = blockIdx.x * blockDim.x + threadIdx.x; i < E; i += gridDim.x * blockDim.x) {
    int p = atomicAdd(&cursor[dst[i]], 1);
    eids[p] = i;
  }
}

// ---------- inl = bf16(node_feat @ Wn + bn) ----------
__global__ __launch_bounds__(256) void node_linear(
    const float* __restrict__ nf, const ushort* __restrict__ wnT,
    const float* __restrict__ bn, ushort* __restrict__ inl, int N) {
  __shared__ ushort Als[64][136];
  __shared__ ushort Bls[128][136];
  int tid = threadIdx.x;
  int n0 = blockIdx.x * 64;
  { // stage B (Wn^T bf16, 128x128)
    int row = tid >> 1, h = tid & 1;
    const uint4* gp = (const uint4*)(wnT + row*128 + h*64);
    uint4* lp = (uint4*)&Bls[row][h*64];
    #pragma unroll
    for (int i = 0; i < 8; ++i) lp[i] = gp[i];
  }
  { // stage A (node_feat f32 -> bf16)
    int r = tid >> 2, q = tid & 3;
    int n = n0 + r;
    uint4* lp = (uint4*)&Als[r][q*32];
    if (n < N) {
      const float4* fp = (const float4*)(nf + (size_t)n*128 + q*32);
      #pragma unroll
      for (int i = 0; i < 4; ++i) lp[i] = pkf8(fp[2*i], fp[2*i+1]);
    } else {
      uint4 z = {0,0,0,0};
      #pragma unroll
      for (int i = 0; i < 4; ++i) lp[i] = z;
    }
  }
  __syncthreads();
  int l = tid & 63, w = tid >> 6, quad = l >> 4, mr = l & 15;
  f32x4 acc[8];
  #pragma unroll
  for (int nt = 0; nt < 8; ++nt) acc[nt] = (f32x4){0.f,0.f,0.f,0.f};
  #pragma unroll
  for (int kk = 0; kk < 4; ++kk) {
    short8 a = *(const short8*)&Als[w*16 + mr][kk*32 + quad*8];
    #pragma unroll
    for (int nt = 0; nt < 8; ++nt) {
      short8 b = *(const short8*)&Bls[nt*16 + mr][kk*32 + quad*8];
      acc[nt] = __builtin_amdgcn_mfma_f32_16x16x32_bf16(a, b, acc[nt], 0, 0, 0);
    }
  }
  #pragma unroll
  for (int nt = 0; nt < 8; ++nt) {
    int col = nt*16 + mr;
    float bias = bn[col];
    #pragma unroll
    for (int rg = 0; rg < 4; ++rg) {
      int n = n0 + w*16 + quad*4 + rg;
      if (n < N) inl[(size_t)n*128 + col] = f2b(acc[nt][rg] + bias);
    }
  }
}

// ---------- cur = relu(inl[src] + ef @ We + be); also emits efb = bf16(ef) ----------
__global__ __launch_bounds__(256) void edge_init(
    const float* __restrict__ ef, const ushort* __restrict__ weT,
    const float* __restrict__ be, const int* __restrict__ esrc,
    const ushort* __restrict__ inl, ushort* __restrict__ cur,
    ushort* __restrict__ efb, int E) {
  __shared__ ushort Als[64][40];    // 64 x 32 (pad 40)
  __shared__ ushort Cls[64][136];   // 64 x 128 (pad 136 = 17x16B)
  int tid = threadIdx.x;
  int e0 = blockIdx.x * 64;
  int l = tid & 63, w = tid >> 6, quad = l >> 4, mr = l & 15;
  int r = tid >> 2, q = tid & 3;

  // B fragments in VGPRs: wave w covers cols [32w, 32w+32) = 2 nt tiles, K=32
  short8 bfrag[2];
  #pragma unroll
  for (int nt = 0; nt < 2; ++nt)
    bfrag[nt] = *(const short8*)(weT + (size_t)(w*32 + nt*16 + mr)*32 + quad*8);

  { // stage A (edge_feat f32 64x32 -> bf16), also write bf16 copy to global
    const float4* fp = (const float4*)(ef + (size_t)(e0 + r)*32 + q*8);
    uint4 pk = pkf8(fp[0], fp[1]);
    *(uint4*)&Als[r][q*8] = pk;
    if (efb) *(uint4*)(efb + (size_t)(e0 + r)*32 + q*8) = pk;
  }
  __syncthreads();

  int col0 = w*32 + mr, col1 = w*32 + 16 + mr;
  float bias0 = be[col0], bias1 = be[col1];
  #pragma unroll
  for (int m = 0; m < 4; ++m) {
    short8 a = *(const short8*)&Als[m*16 + mr][quad*8];
    f32x4 zero = (f32x4){0.f,0.f,0.f,0.f};
    f32x4 acc0 = __builtin_amdgcn_mfma_f32_16x16x32_bf16(a, bfrag[0], zero, 0, 0, 0);
    f32x4 acc1 = __builtin_amdgcn_mfma_f32_16x16x32_bf16(a, bfrag[1], zero, 0, 0, 0);
    #pragma unroll
    for (int rg = 0; rg < 4; ++rg) {
      int row = m*16 + quad*4 + rg;
      Cls[row][col0] = f2b(acc0[rg] + bias0);
      Cls[row][col1] = f2b(acc1[rg] + bias1);
    }
  }
  __syncthreads();

  { // packed epilogue: cur[e] = relu(C + inl[src[e]])
    int e = e0 + r;
    int s = esrc[e];
    const uint4* cl = (const uint4*)&Cls[r][q*32];
    const uint4* ip = (const uint4*)(inl + (size_t)s*128 + q*32);
    uint4* op = (uint4*)(cur + (size_t)e*128 + q*32);
    #pragma unroll
    for (int i = 0; i < 4; ++i) op[i] = addrelu8(cl[i], ip[i]);
  }
}

// ---------- segment-sum of cur rows into nodes via CSR (8-deep unroll) ----------
__global__ __launch_bounds__(256) void segsum(
    const ushort* __restrict__ cur, const int* __restrict__ off,
    const int* __restrict__ eids, ushort* __restrict__ nagg, int N) {
  int w = threadIdx.x >> 6, l = threadIdx.x & 63;
  int n = blockIdx.x * 4 + w;
  if (n >= N) return;
  int i = off[n], end = off[n + 1];
  float s0 = 0.f, s1 = 0.f;
  for (; i + 8 <= end; i += 8) {
    int e[8]; uint v[8];
    #pragma unroll
    for (int j = 0; j < 8; ++j) e[j] = eids[i + j];
    #pragma unroll
    for (int j = 0; j < 8; ++j) v[j] = *(const uint*)(cur + (size_t)e[j]*128 + 2*l);
    #pragma unroll
    for (int j = 0; j < 8; ++j) { s0 += lo2f(v[j]); s1 += hi2f(v[j]); }
  }
  for (; i < end; ++i) {
    int ea = eids[i];
    uint va = *(const uint*)(cur + (size_t)ea*128 + 2*l);
    s0 += lo2f(va); s1 += hi2f(va);
  }
  *(uint*)(nagg + (size_t)n*128 + 2*l) = pk2(s0, s1);
}

// ---------- cur = relu([nagg[src]-cur[e^1] | ef] @ [Wc|We]^T + (cb+be) + inl[src]) ----------
// K = 160. B slice per wave in VGPRs; single LDS tile reused: A (64x160) for the
// MFMA phase, then C (64x128) written into the same rows -> 21.5 KB LDS, 7 blocks/CU.
__global__ __launch_bounds__(256) void conv_step(
    ushort* __restrict__ cur, const ushort* __restrict__ nagg,
    const ushort* __restrict__ inl, const ushort* __restrict__ efb,
    const float* __restrict__ ef, const ushort* __restrict__ cweT,
    const float* __restrict__ cbe, const int* __restrict__ esrc, int E) {
  __shared__ ushort Als[64][168];   // A: 64x160 (pad->168 = 21x16B); C reuses cols [0,128)
  int tid = threadIdx.x;
  int e0 = blockIdx.x * 64;
  int l = tid & 63, w = tid >> 6, quad = l >> 4, mr = l & 15;
  int r = tid >> 2, q = tid & 3;

  // B fragments: wave w covers output cols [32w, 32w+32) = 2 nt tiles, K=160
  short8 bfrag[2][5];
  #pragma unroll
  for (int nt = 0; nt < 2; ++nt) {
    const ushort* bp = cweT + (size_t)(w*32 + nt*16 + mr) * 160;
    #pragma unroll
    for (int kk = 0; kk < 5; ++kk)
      bfrag[nt][kk] = *(const short8*)(bp + kk*32 + quad*8);
  }

  { // stage A: cols[0,128) = nagg[src[e]] - cur[e^1]; cols[128,160) = bf16 edge feat
    int e = e0 + r;
    int s = esrc[e];
    const uint4* cp = (const uint4*)(cur + (size_t)(e ^ 1)*128 + q*32);
    const uint4* np = (const uint4*)(nagg + (size_t)s*128 + q*32);
    uint4* lp = (uint4*)&Als[r][q*32];
    #pragma unroll
    for (int i = 0; i < 4; ++i) lp[i] = sub8(np[i], cp[i]);
    if (efb) {
      *(uint4*)&Als[r][128 + q*8] = *(const uint4*)(efb + (size_t)e*32 + q*8);
    } else {
      const float4* fp = (const float4*)(ef + (size_t)e*32 + q*8);
      *(uint4*)&Als[r][128 + q*8] = pkf8(fp[0], fp[1]);
    }
  }
  __syncthreads();

  int col0 = w*32 + mr, col1 = w*32 + 16 + mr;
  float bias0 = cbe[col0], bias1 = cbe[col1];
  f32x4 acc0[4], acc1[4];
  #pragma unroll
  for (int m = 0; m < 4; ++m) {
    acc0[m] = (f32x4){0.f,0.f,0.f,0.f};
    acc1[m] = (f32x4){0.f,0.f,0.f,0.f};
    #pragma unroll
    for (int kk = 0; kk < 5; ++kk) {
      short8 a = *(const short8*)&Als[m*16 + mr][kk*32 + quad*8];
      acc0[m] = __builtin_amdgcn_mfma_f32_16x16x32_bf16(a, bfrag[0][kk], acc0[m], 0, 0, 0);
      acc1[m] = __builtin_amdgcn_mfma_f32_16x16x32_bf16(a, bfrag[1][kk], acc1[m], 0, 0, 0);
    }
  }
  __syncthreads();  // all A reads done -> safe to overwrite Als with C

  #pragma unroll
  for (int m = 0; m < 4; ++m) {
    #pragma unroll
    for (int rg = 0; rg < 4; ++rg) {
      int row = m*16 + quad*4 + rg;
      Als[row][col0] = f2b(acc0[m][rg] + bias0);
      Als[row][col1] = f2b(acc1[m][rg] + bias1);
    }
  }
  __syncthreads();

  { // packed epilogue: cur[e] = relu(C + inl[src[e]])  (cur reads all done pre-barrier)
    int e = e0 + r;
    int s = esrc[e];
    const uint4* cl = (const uint4*)&Als[r][q*32];
    const uint4* ip = (const uint4*)(inl + (size_t)s*128 + q*32);
    uint4* op = (uint4*)(cur + (size_t)e*128 + q*32);
    #pragma unroll
    for (int i = 0; i < 4; ++i) op[i] = addrelu8(cl[i], ip[i]);
  }
}

// ---------- ract(bf16) = relu(relu(nagg) @ Wo + ob) ----------
__global__ __launch_bounds__(256) void out_linear(
    const ushort* __restrict__ nagg, const ushort* __restrict__ owT,
    const float* __restrict__ ob, ushort* __restrict__ ract, int N) {
  __shared__ ushort Als[64][136];
  __shared__ ushort Bls[128][136];
  int tid = threadIdx.x;
  int n0 = blockIdx.x * 64;
  {
    int row = tid >> 1, h = tid & 1;
    const uint4* gp = (const uint4*)(owT + row*128 + h*64);
    uint4* lp = (uint4*)&Bls[row][h*64];
    #pragma unroll
    for (int i = 0; i < 8; ++i) lp[i] = gp[i];
  }
  {
    int r = tid >> 2, q = tid & 3;
    int n = n0 + r;
    uint4* lp = (uint4*)&Als[r][q*32];
    if (n < N) {
      const uint4* gp = (const uint4*)(nagg + (size_t)n*128 + q*32);
      #pragma unroll
      for (int i = 0; i < 4; ++i) lp[i] = relu8(gp[i]);
    } else {
      uint4 z = {0,0,0,0};
      #pragma unroll
      for (int i = 0; i < 4; ++i) lp[i] = z;
    }
  }
  __syncthreads();
  int l = tid & 63, w = tid >> 6, quad = l >> 4, mr = l & 15;
  f32x4 acc[8];
  #pragma unroll
  for (int nt = 0; nt < 8; ++nt) acc[nt] = (f32x4){0.f,0.f,0.f,0.f};
  #pragma unroll
  for (int kk = 0; kk < 4; ++kk) {
    short8 a = *(const short8*)&Als[w*16 + mr][kk*32 + quad*8];
    #pragma unroll
    for (int nt = 0; nt < 8; ++nt) {
      short8 b = *(const short8*)&Bls[nt*16 + mr][kk*32 + quad*8];
      acc[nt] = __builtin_amdgcn_mfma_f32_16x16x32_bf16(a, b, acc[nt], 0, 0, 0);
    }
  }
  #pragma unroll
  for (int nt = 0; nt < 8; ++nt) {
    int col = nt*16 + mr;
    float bias = ob[col];
    #pragma unroll
    for (int rg = 0; rg < 4; ++rg) {
      int n = n0 + w*16 + quad*4 + rg;
      if (n < N) ract[(size_t)n*128 + col] = f2b(fmaxf(acc[nt][rg] + bias, 0.f));
    }
  }
}

// ---------- per-graph node ranges (graph_ids is sorted), parallel ----------
__global__ void graph_offsets(const int* __restrict__ gids, int* __restrict__ goff,
                              int N, int G) {
  int i = blockIdx.x * blockDim.x + threadIdx.x;
  if (i > N) return;
  int pg = (i == 0) ? -1 : gids[i - 1];
  int cg = (i == N) ? G : gids[i];
  for (int g = pg + 1; g <= cg; ++g) goff[g] = i;
}

// ---------- pool nodes per graph (bf16 in, f32 out) ----------
__global__ __launch_bounds__(256) void graph_pool(
    const ushort* __restrict__ ract, const int* __restrict__ goff,
    float* __restrict__ out, int G) {
  __shared__ float red0[256];
  __shared__ float red1[256];
  int g = blockIdx.x;
  int t = threadIdx.x;
  int c2 = t & 63, rp = t >> 6;      // 2 cols per lane, 4 row-partitions
  int beg = goff[g], end = goff[g + 1];
  float s0 = 0.f, s1 = 0.f;
  for (int n = beg + rp; n < end; n += 4) {
    uint v = *(const uint*)(ract + (size_t)n*128 + 2*c2);
    s0 += lo2f(v); s1 += hi2f(v);
  }
  red0[t] = s0; red1[t] = s1;
  __syncthreads();
  if (rp == 0) {
    float v0 = red0[c2] + red0[c2 + 64] + red0[c2 + 128] + red0[c2 + 192];
    float v1 = red1[c2] + red1[c2 + 64] + red1[c2 + 128] + red1[c2 + 192];
    float2 o; o.x = fmaxf(v0, 0.f); o.y = fmaxf(v1, 0.f);
    *(float2*)(out + (size_t)g*128 + 2*c2) = o;
  }
}

extern "C" void kernel_launch(void* const* d_in, const int* in_sizes, int n_in,
                              void* d_out, int out_size, void* d_ws, size_t ws_size,
                              hipStream_t stream) {
  const float* node_feat = (const float*)d_in[0];
  const float* edge_feat = (const float*)d_in[1];
  const float* wn = (const float*)d_in[2];
  const float* bn = (const float*)d_in[3];
  const float* we = (const float*)d_in[4];
  const float* be = (const float*)d_in[5];
  const float* cw = (const float*)d_in[6];
  const float* cb = (const float*)d_in[7];
  const float* ow = (const float*)d_in[8];
  const float* ob = (const float*)d_in[9];
  const int* esrc = (const int*)d_in[10];
  const int* edst = (const int*)d_in[11];
  const int* gids = (const int*)d_in[12];
  int N = in_sizes[0] / 128;
  int E = in_sizes[10];
  int G = out_size / 128;
  float* out = (float*)d_out;

  char* p = (char*)d_ws;
  auto alloc = [&](size_t bytes) {
    char* r = p;
    p += (bytes + 255) & ~(size_t)255;
    return r;
  };
  // core ws: ~234 MB; efb adds 51.2 MB (guarded against ws_size)
  ushort* cur     = (ushort*)alloc((size_t)E * 128 * 2);
  ushort* inl     = (ushort*)alloc((size_t)N * 128 * 2);   // reused as ract after last conv
  ushort* nagg    = (ushort*)alloc((size_t)N * 128 * 2);
  int*    eids    = (int*)   alloc((size_t)E * 4);
  int*    counts  = (int*)   alloc((size_t)N * 4);
  int*    off     = (int*)   alloc((size_t)(N + 1) * 4);
  int*    cursor  = (int*)   alloc((size_t)N * 4);
  int*    goff    = (int*)   alloc((size_t)(G + 1) * 4);
  ushort* wnT     = (ushort*)alloc(128 * 128 * 2);
  ushort* weT     = (ushort*)alloc(128 * 32 * 2);
  ushort* cweT    = (ushort*)alloc(128 * 160 * 2);
  ushort* owT     = (ushort*)alloc(128 * 128 * 2);
  float*  cbe     = (float*) alloc(128 * 4);
  ushort* efb     = (ushort*)alloc((size_t)E * 32 * 2);    // bf16 edge features
  if ((size_t)(p - (char*)d_ws) > ws_size) efb = nullptr;  // fallback: read f32 ef in conv
  ushort* ract    = inl;  // alias: inl dead after last conv_step
  (void)n_in;

  zero_ints<<<(N + 255) / 256, 256, 0, stream>>>(counts, N);
  prep_weights<<<225, 256, 0, stream>>>(wn, we, cw, ow, cb, be, wnT, weT, cweT, owT, cbe);
  count_dst<<<1024, 256, 0, stream>>>(edst, counts, E);
  scan_offsets<<<1, 1024, 0, stream>>>(counts, off, cursor, N);
  fill_csr<<<1024, 256, 0, stream>>>(edst, cursor, eids, E);

  node_linear<<<(N + 63) / 64, 256, 0, stream>>>(node_feat, wnT, bn, inl, N);
  edge_init<<<E / 64, 256, 0, stream>>>(edge_feat, weT, be, esrc, inl, cur, efb, E);

  for (int it = 0; it < 3; ++it) {
    segsum<<<(N + 3) / 4, 256, 0, stream>>>(cur, off, eids, nagg, N);
    conv_step<<<E / 64, 256, 0, stream>>>(cur, nagg, inl, efb, edge_feat, cweT, cbe, esrc, E);
  }
  segsum<<<(N + 3) / 4, 256, 0, stream>>>(cur, off, eids, nagg, N);
  out_linear<<<(N + 63) / 64, 256, 0, stream>>>(nagg, owT, ob, ract, N);
  graph_offsets<<<(N + 256) / 256, 256, 0, stream>>>(gids, goff, N, G);
  graph_pool<<<G, 256, 0, stream>>>(ract, goff, out, G);
}

// Round 6
// 1152.684 us; speedup vs baseline: 1.0308x; 1.0308x over previous
//
#include <hip/hip_runtime.h>
#include <hip/hip_bf16.h>
#include <stdint.h>

typedef __attribute__((ext_vector_type(8))) short short8;
typedef __attribute__((ext_vector_type(4))) float f32x4;

#if defined(__has_builtin)
#if __has_builtin(__builtin_amdgcn_cvt_pk_bf16_f32)
#define HAVE_PK_BF16 1
#endif
#endif

__device__ __forceinline__ float b2f(ushort u) {
  union { uint32_t i; float f; } v; v.i = ((uint32_t)u) << 16; return v.f;
}
__device__ __forceinline__ ushort f2b_sw(float f) {
  union { float f; uint32_t i; } v; v.f = f;
  uint32_t x = v.i;
  uint32_t r = x + 0x7FFFu + ((x >> 16) & 1u);
  return (ushort)(r >> 16);
}
__device__ __forceinline__ uint pk2(float lo, float hi) {
#ifdef HAVE_PK_BF16
  auto r = __builtin_amdgcn_cvt_pk_bf16_f32(lo, hi);
  union { decltype(r) v; uint u; } c; c.v = r; return c.u;
#else
  return (uint)f2b_sw(lo) | ((uint)f2b_sw(hi) << 16);
#endif
}
__device__ __forceinline__ ushort f2b(float f) {
#ifdef HAVE_PK_BF16
  return (ushort)(pk2(f, 0.f) & 0xFFFFu);
#else
  return f2b_sw(f);
#endif
}
__device__ __forceinline__ float lo2f(uint v) { return b2f((ushort)(v & 0xFFFFu)); }
__device__ __forceinline__ float hi2f(uint v) { return b2f((ushort)(v >> 16)); }

__device__ __forceinline__ uint4 pkf8(float4 a, float4 b) {
  uint4 o;
  o.x = pk2(a.x, a.y); o.y = pk2(a.z, a.w);
  o.z = pk2(b.x, b.y); o.w = pk2(b.z, b.w);
  return o;
}
__device__ __forceinline__ uint sub2(uint a, uint b) {
  return pk2(lo2f(a) - lo2f(b), hi2f(a) - hi2f(b));
}
__device__ __forceinline__ uint4 sub8(uint4 a, uint4 b) {
  uint4 o; o.x = sub2(a.x,b.x); o.y = sub2(a.y,b.y); o.z = sub2(a.z,b.z); o.w = sub2(a.w,b.w); return o;
}
__device__ __forceinline__ uint addrelu2(uint a, uint b) {
  return pk2(fmaxf(lo2f(a) + lo2f(b), 0.f), fmaxf(hi2f(a) + hi2f(b), 0.f));
}
__device__ __forceinline__ uint4 addrelu8(uint4 a, uint4 b) {
  uint4 o; o.x = addrelu2(a.x,b.x); o.y = addrelu2(a.y,b.y);
  o.z = addrelu2(a.z,b.z); o.w = addrelu2(a.w,b.w); return o;
}
__device__ __forceinline__ uint relu2(uint v) {
  uint lo = (v & 0x8000u) ? 0u : (v & 0xFFFFu);
  uint hi = (v & 0x80000000u) ? 0u : (v & 0xFFFF0000u);
  return lo | hi;
}
__device__ __forceinline__ uint4 relu8(uint4 v) {
  uint4 o; o.x = relu2(v.x); o.y = relu2(v.y); o.z = relu2(v.z); o.w = relu2(v.w); return o;
}

__global__ void zero_ints(int* __restrict__ p, int n) {
  int i = blockIdx.x * blockDim.x + threadIdx.x;
  if (i < n) p[i] = 0;
}

// ---------- weight prep ----------
__global__ void prep_weights(const float* __restrict__ wn, const float* __restrict__ we,
                             const float* __restrict__ cw, const float* __restrict__ ow,
                             const float* __restrict__ cb, const float* __restrict__ be,
                             ushort* __restrict__ wnT, ushort* __restrict__ weT,
                             ushort* __restrict__ cweT, ushort* __restrict__ owT,
                             float* __restrict__ cbe) {
  int i = blockIdx.x * blockDim.x + threadIdx.x;
  if (i < 16384) {
    int n = i >> 7, k = i & 127; wnT[n*128+k] = f2b(wn[k*128+n]);
  } else if (i < 32768) {
    int j = i - 16384; int n = j >> 7, k = j & 127; owT[n*128+k] = f2b(ow[k*128+n]);
  } else if (i < 53248) {
    int j = i - 32768;           // 128*160 entries
    int n = j / 160, k = j % 160;
    cweT[n*160+k] = (k < 128) ? f2b(cw[k*128+n]) : f2b(we[(k-128)*128+n]);
  } else if (i < 57344) {
    int j = i - 53248; int n = j >> 5, k = j & 31; weT[n*32+k] = f2b(we[k*128+n]);
  } else if (i < 57472) {
    int j = i - 57344; cbe[j] = cb[j] + be[j];
  }
}

// ---------- CSR build ----------
__global__ void count_dst(const int* __restrict__ dst, int* __restrict__ counts, int E) {
  for (int i = blockIdx.x * blockDim.x + threadIdx.x; i < E; i += gridDim.x * blockDim.x)
    atomicAdd(&counts[dst[i]], 1);
}
__global__ __launch_bounds__(1024) void scan_offsets(
    const int* __restrict__ counts, int* __restrict__ off,
    int* __restrict__ cursor, int N) {
  __shared__ int part[1024];
  int t = threadIdx.x;
  int chunk = (N + 1023) >> 10;
  int lo = t * chunk, hi = min(lo + chunk, N);
  int s = 0;
  for (int i = lo; i < hi; ++i) s += counts[i];
  part[t] = s;
  __syncthreads();
  for (int d = 1; d < 1024; d <<= 1) {
    int v = (t >= d) ? part[t - d] : 0;
    __syncthreads();
    part[t] += v;
    __syncthreads();
  }
  int run = (t > 0) ? part[t - 1] : 0;
  for (int i = lo; i < hi; ++i) {
    off[i] = run; cursor[i] = run; run += counts[i];
  }
  if (t == 1023) off[N] = part[1023];
}
__global__ void fill_csr(const int* __restrict__ dst, int* __restrict__ cursor,
                         int* __restrict__ eids, int E) {
  for (int i = blockIdx.x * blockDim.x + threadIdx.x; i < E; i += gridDim.x * blockDim.x) {
    int p = atomicAdd(&cursor[dst[i]], 1);
    eids[p] = i;
  }
}

// ---------- ni[:,128:256) = bf16(node_feat @ Wn + bn) ----------
__global__ __launch_bounds__(256) void node_linear(
    const float* __restrict__ nf, const ushort* __restrict__ wnT,
    const float* __restrict__ bn, ushort* __restrict__ ni, int N) {
  __shared__ ushort Als[64][136];
  __shared__ ushort Bls[128][136];
  int tid = threadIdx.x;
  int n0 = blockIdx.x * 64;
  {
    int row = tid >> 1, h = tid & 1;
    const uint4* gp = (const uint4*)(wnT + row*128 + h*64);
    uint4* lp = (uint4*)&Bls[row][h*64];
    #pragma unroll
    for (int i = 0; i < 8; ++i) lp[i] = gp[i];
  }
  {
    int r = tid >> 2, q = tid & 3;
    int n = n0 + r;
    uint4* lp = (uint4*)&Als[r][q*32];
    if (n < N) {
      const float4* fp = (const float4*)(nf + (size_t)n*128 + q*32);
      #pragma unroll
      for (int i = 0; i < 4; ++i) lp[i] = pkf8(fp[2*i], fp[2*i+1]);
    } else {
      uint4 z = {0,0,0,0};
      #pragma unroll
      for (int i = 0; i < 4; ++i) lp[i] = z;
    }
  }
  __syncthreads();
  int l = tid & 63, w = tid >> 6, quad = l >> 4, mr = l & 15;
  f32x4 acc[8];
  #pragma unroll
  for (int nt = 0; nt < 8; ++nt) acc[nt] = (f32x4){0.f,0.f,0.f,0.f};
  #pragma unroll
  for (int kk = 0; kk < 4; ++kk) {
    short8 a = *(const short8*)&Als[w*16 + mr][kk*32 + quad*8];
    #pragma unroll
    for (int nt = 0; nt < 8; ++nt) {
      short8 b = *(const short8*)&Bls[nt*16 + mr][kk*32 + quad*8];
      acc[nt] = __builtin_amdgcn_mfma_f32_16x16x32_bf16(a, b, acc[nt], 0, 0, 0);
    }
  }
  #pragma unroll
  for (int nt = 0; nt < 8; ++nt) {
    int col = nt*16 + mr;
    float bias = bn[col];
    #pragma unroll
    for (int rg = 0; rg < 4; ++rg) {
      int n = n0 + w*16 + quad*4 + rg;
      if (n < N) ni[(size_t)n*256 + 128 + col] = f2b(acc[nt][rg] + bias);
    }
  }
}

// ---------- cur = relu(inl[src] + ef @ We + be); emits efb = bf16(ef) ----------
__global__ __launch_bounds__(256) void edge_init(
    const float* __restrict__ ef, const ushort* __restrict__ weT,
    const float* __restrict__ be, const int* __restrict__ esrc,
    const ushort* __restrict__ ni, ushort* __restrict__ cur,
    ushort* __restrict__ efb, int E) {
  __shared__ ushort Als[64][40];
  __shared__ ushort Cls[64][136];
  int tid = threadIdx.x;
  int e0 = blockIdx.x * 64;
  int l = tid & 63, w = tid >> 6, quad = l >> 4, mr = l & 15;
  int r = tid >> 2, q = tid & 3;

  short8 bfrag[2];
  #pragma unroll
  for (int nt = 0; nt < 2; ++nt)
    bfrag[nt] = *(const short8*)(weT + (size_t)(w*32 + nt*16 + mr)*32 + quad*8);

  int e = e0 + r;
  int s = esrc[e];
  { // stage A (edge_feat f32 -> bf16) + efb emit
    const float4* fp = (const float4*)(ef + (size_t)e*32 + q*8);
    uint4 pk = pkf8(fp[0], fp[1]);
    *(uint4*)&Als[r][q*8] = pk;
    if (efb) *(uint4*)(efb + (size_t)e*32 + q*8) = pk;
  }
  // prefetch epilogue inl row (hidden under MFMA phase)
  uint4 irow[4];
  {
    const uint4* ip = (const uint4*)(ni + (size_t)s*256 + 128 + q*32);
    #pragma unroll
    for (int i = 0; i < 4; ++i) irow[i] = ip[i];
  }
  __syncthreads();

  int col0 = w*32 + mr, col1 = w*32 + 16 + mr;
  float bias0 = be[col0], bias1 = be[col1];
  #pragma unroll
  for (int m = 0; m < 4; ++m) {
    short8 a = *(const short8*)&Als[m*16 + mr][quad*8];
    f32x4 zero = (f32x4){0.f,0.f,0.f,0.f};
    f32x4 acc0 = __builtin_amdgcn_mfma_f32_16x16x32_bf16(a, bfrag[0], zero, 0, 0, 0);
    f32x4 acc1 = __builtin_amdgcn_mfma_f32_16x16x32_bf16(a, bfrag[1], zero, 0, 0, 0);
    #pragma unroll
    for (int rg = 0; rg < 4; ++rg) {
      int row = m*16 + quad*4 + rg;
      Cls[row][col0] = f2b(acc0[rg] + bias0);
      Cls[row][col1] = f2b(acc1[rg] + bias1);
    }
  }
  __syncthreads();

  { // packed epilogue: cur[e] = relu(C + inl_row)
    const uint4* cl = (const uint4*)&Cls[r][q*32];
    uint4* op = (uint4*)(cur + (size_t)e*128 + q*32);
    #pragma unroll
    for (int i = 0; i < 4; ++i) op[i] = addrelu8(cl[i], irow[i]);
  }
}

// ---------- segment-sum: 2 edges per load instr (uint2/lane), 8-pair unroll ----------
__global__ __launch_bounds__(256) void segsum(
    const ushort* __restrict__ cur, const int* __restrict__ off,
    const int* __restrict__ eids, ushort* __restrict__ ni, int N) {
  int w = threadIdx.x >> 6, l = threadIdx.x & 63;
  int n = blockIdx.x * 4 + w;
  if (n >= N) return;
  int c8 = l & 31;     // 8-byte chunk index (4 bf16 cols)
  int half = l >> 5;   // which edge of the pair
  int beg = off[n], end = off[n + 1];
  float s0 = 0.f, s1 = 0.f, s2 = 0.f, s3 = 0.f;
  int i = beg;
  for (; i + 16 <= end; i += 16) {
    uint2 v[8];
    #pragma unroll
    for (int j = 0; j < 8; ++j) {
      int e = eids[i + 2*j + half];
      v[j] = *(const uint2*)(cur + (size_t)e*128 + c8*4);
    }
    #pragma unroll
    for (int j = 0; j < 8; ++j) {
      s0 += lo2f(v[j].x); s1 += hi2f(v[j].x);
      s2 += lo2f(v[j].y); s3 += hi2f(v[j].y);
    }
  }
  for (; i + 2 <= end; i += 2) {
    int e = eids[i + half];
    uint2 v = *(const uint2*)(cur + (size_t)e*128 + c8*4);
    s0 += lo2f(v.x); s1 += hi2f(v.x); s2 += lo2f(v.y); s3 += hi2f(v.y);
  }
  if (i < end && half == 0) {
    int e = eids[i];
    uint2 v = *(const uint2*)(cur + (size_t)e*128 + c8*4);
    s0 += lo2f(v.x); s1 += hi2f(v.x); s2 += lo2f(v.y); s3 += hi2f(v.y);
  }
  s0 += __shfl_xor(s0, 32); s1 += __shfl_xor(s1, 32);
  s2 += __shfl_xor(s2, 32); s3 += __shfl_xor(s3, 32);
  if (half == 0) {
    uint2 o; o.x = pk2(s0, s1); o.y = pk2(s2, s3);
    *(uint2*)(ni + (size_t)n*256 + c8*4) = o;
  }
}

// ---------- cur = relu([nagg[src]-cur[e^1] | efb] @ [Wc|We]^T + (cb+be) + inl[src]) ----------
// ni row: [0,128)=nagg, [128,256)=inl -> both gathers share one 512B region.
// inl row prefetched into regs before the MFMA phase (phase-3 stall removed).
__global__ __launch_bounds__(256) void conv_step(
    ushort* __restrict__ cur, const ushort* __restrict__ ni,
    const ushort* __restrict__ efb, const float* __restrict__ ef,
    const ushort* __restrict__ cweT, const float* __restrict__ cbe,
    const int* __restrict__ esrc, int E) {
  __shared__ ushort Als[64][168];   // A: 64x160; C reuses cols [0,128)
  int tid = threadIdx.x;
  int e0 = blockIdx.x * 64;
  int l = tid & 63, w = tid >> 6, quad = l >> 4, mr = l & 15;
  int r = tid >> 2, q = tid & 3;

  short8 bfrag[2][5];
  #pragma unroll
  for (int nt = 0; nt < 2; ++nt) {
    const ushort* bp = cweT + (size_t)(w*32 + nt*16 + mr) * 160;
    #pragma unroll
    for (int kk = 0; kk < 5; ++kk)
      bfrag[nt][kk] = *(const short8*)(bp + kk*32 + quad*8);
  }

  int e = e0 + r;
  int s = esrc[e];
  { // stage A: cols[0,128) = nagg[src] - cur[e^1]; cols[128,160) = bf16 edge feat
    const uint4* cp = (const uint4*)(cur + (size_t)(e ^ 1)*128 + q*32);
    const uint4* np = (const uint4*)(ni + (size_t)s*256 + q*32);
    uint4* lp = (uint4*)&Als[r][q*32];
    #pragma unroll
    for (int i = 0; i < 4; ++i) lp[i] = sub8(np[i], cp[i]);
    if (efb) {
      *(uint4*)&Als[r][128 + q*8] = *(const uint4*)(efb + (size_t)e*32 + q*8);
    } else {
      const float4* fp = (const float4*)(ef + (size_t)e*32 + q*8);
      *(uint4*)&Als[r][128 + q*8] = pkf8(fp[0], fp[1]);
    }
  }
  // prefetch epilogue inl row (adjacent half of the same ni row)
  uint4 irow[4];
  {
    const uint4* ip = (const uint4*)(ni + (size_t)s*256 + 128 + q*32);
    #pragma unroll
    for (int i = 0; i < 4; ++i) irow[i] = ip[i];
  }
  __syncthreads();

  int col0 = w*32 + mr, col1 = w*32 + 16 + mr;
  float bias0 = cbe[col0], bias1 = cbe[col1];
  f32x4 acc0[4], acc1[4];
  #pragma unroll
  for (int m = 0; m < 4; ++m) {
    acc0[m] = (f32x4){0.f,0.f,0.f,0.f};
    acc1[m] = (f32x4){0.f,0.f,0.f,0.f};
    #pragma unroll
    for (int kk = 0; kk < 5; ++kk) {
      short8 a = *(const short8*)&Als[m*16 + mr][kk*32 + quad*8];
      acc0[m] = __builtin_amdgcn_mfma_f32_16x16x32_bf16(a, bfrag[0][kk], acc0[m], 0, 0, 0);
      acc1[m] = __builtin_amdgcn_mfma_f32_16x16x32_bf16(a, bfrag[1][kk], acc1[m], 0, 0, 0);
    }
  }
  __syncthreads();  // all A reads done -> overwrite Als with C

  #pragma unroll
  for (int m = 0; m < 4; ++m) {
    #pragma unroll
    for (int rg = 0; rg < 4; ++rg) {
      int row = m*16 + quad*4 + rg;
      Als[row][col0] = f2b(acc0[m][rg] + bias0);
      Als[row][col1] = f2b(acc1[m][rg] + bias1);
    }
  }
  __syncthreads();

  { // packed epilogue: cur[e] = relu(C + inl_row)  (inl already in regs)
    const uint4* cl = (const uint4*)&Als[r][q*32];
    uint4* op = (uint4*)(cur + (size_t)e*128 + q*32);
    #pragma unroll
    for (int i = 0; i < 4; ++i) op[i] = addrelu8(cl[i], irow[i]);
  }
}

// ---------- ract(bf16) = relu(relu(nagg) @ Wo + ob) ----------
__global__ __launch_bounds__(256) void out_linear(
    const ushort* __restrict__ ni, const ushort* __restrict__ owT,
    const float* __restrict__ ob, ushort* __restrict__ ract, int N) {
  __shared__ ushort Als[64][136];
  __shared__ ushort Bls[128][136];
  int tid = threadIdx.x;
  int n0 = blockIdx.x * 64;
  {
    int row = tid >> 1, h = tid & 1;
    const uint4* gp = (const uint4*)(owT + row*128 + h*64);
    uint4* lp = (uint4*)&Bls[row][h*64];
    #pragma unroll
    for (int i = 0; i < 8; ++i) lp[i] = gp[i];
  }
  {
    int r = tid >> 2, q = tid & 3;
    int n = n0 + r;
    uint4* lp = (uint4*)&Als[r][q*32];
    if (n < N) {
      const uint4* gp = (const uint4*)(ni + (size_t)n*256 + q*32);
      #pragma unroll
      for (int i = 0; i < 4; ++i) lp[i] = relu8(gp[i]);
    } else {
      uint4 z = {0,0,0,0};
      #pragma unroll
      for (int i = 0; i < 4; ++i) lp[i] = z;
    }
  }
  __syncthreads();
  int l = tid & 63, w = tid >> 6, quad = l >> 4, mr = l & 15;
  f32x4 acc[8];
  #pragma unroll
  for (int nt = 0; nt < 8; ++nt) acc[nt] = (f32x4){0.f,0.f,0.f,0.f};
  #pragma unroll
  for (int kk = 0; kk < 4; ++kk) {
    short8 a = *(const short8*)&Als[w*16 + mr][kk*32 + quad*8];
    #pragma unroll
    for (int nt = 0; nt < 8; ++nt) {
      short8 b = *(const short8*)&Bls[nt*16 + mr][kk*32 + quad*8];
      acc[nt] = __builtin_amdgcn_mfma_f32_16x16x32_bf16(a, b, acc[nt], 0, 0, 0);
    }
  }
  #pragma unroll
  for (int nt = 0; nt < 8; ++nt) {
    int col = nt*16 + mr;
    float bias = ob[col];
    #pragma unroll
    for (int rg = 0; rg < 4; ++rg) {
      int n = n0 + w*16 + quad*4 + rg;
      if (n < N) ract[(size_t)n*128 + col] = f2b(fmaxf(acc[nt][rg] + bias, 0.f));
    }
  }
}

// ---------- per-graph node ranges (graph_ids is sorted), parallel ----------
__global__ void graph_offsets(const int* __restrict__ gids, int* __restrict__ goff,
                              int N, int G) {
  int i = blockIdx.x * blockDim.x + threadIdx.x;
  if (i > N) return;
  int pg = (i == 0) ? -1 : gids[i - 1];
  int cg = (i == N) ? G : gids[i];
  for (int g = pg + 1; g <= cg; ++g) goff[g] = i;
}

// ---------- pool nodes per graph (bf16 in, f32 out) ----------
__global__ __launch_bounds__(256) void graph_pool(
    const ushort* __restrict__ ract, const int* __restrict__ goff,
    float* __restrict__ out, int G) {
  __shared__ float red0[256];
  __shared__ float red1[256];
  int g = blockIdx.x;
  int t = threadIdx.x;
  int c2 = t & 63, rp = t >> 6;
  int beg = goff[g], end = goff[g + 1];
  float s0 = 0.f, s1 = 0.f;
  for (int n = beg + rp; n < end; n += 4) {
    uint v = *(const uint*)(ract + (size_t)n*128 + 2*c2);
    s0 += lo2f(v); s1 += hi2f(v);
  }
  red0[t] = s0; red1[t] = s1;
  __syncthreads();
  if (rp == 0) {
    float v0 = red0[c2] + red0[c2 + 64] + red0[c2 + 128] + red0[c2 + 192];
    float v1 = red1[c2] + red1[c2 + 64] + red1[c2 + 128] + red1[c2 + 192];
    float2 o; o.x = fmaxf(v0, 0.f); o.y = fmaxf(v1, 0.f);
    *(float2*)(out + (size_t)g*128 + 2*c2) = o;
  }
}

extern "C" void kernel_launch(void* const* d_in, const int* in_sizes, int n_in,
                              void* d_out, int out_size, void* d_ws, size_t ws_size,
                              hipStream_t stream) {
  const float* node_feat = (const float*)d_in[0];
  const float* edge_feat = (const float*)d_in[1];
  const float* wn = (const float*)d_in[2];
  const float* bn = (const float*)d_in[3];
  const float* we = (const float*)d_in[4];
  const float* be = (const float*)d_in[5];
  const float* cw = (const float*)d_in[6];
  const float* cb = (const float*)d_in[7];
  const float* ow = (const float*)d_in[8];
  const float* ob = (const float*)d_in[9];
  const int* esrc = (const int*)d_in[10];
  const int* edst = (const int*)d_in[11];
  const int* gids = (const int*)d_in[12];
  int N = in_sizes[0] / 128;
  int E = in_sizes[10];
  int G = out_size / 128;
  float* out = (float*)d_out;

  char* p = (char*)d_ws;
  auto alloc = [&](size_t bytes) {
    char* r = p;
    p += (bytes + 255) & ~(size_t)255;
    return r;
  };
  // ws: cur 204.8 + ni 25.6 + eids 3.2 + ints ~0.6 + weights ~0.12 + efb 51.2 ~= 286 MB
  ushort* cur     = (ushort*)alloc((size_t)E * 128 * 2);
  ushort* ni      = (ushort*)alloc((size_t)N * 256 * 2);   // [nagg | inl] interleaved
  int*    eids    = (int*)   alloc((size_t)E * 4);
  int*    counts  = (int*)   alloc((size_t)N * 4);
  int*    off     = (int*)   alloc((size_t)(N + 1) * 4);
  int*    cursor  = (int*)   alloc((size_t)N * 4);
  int*    goff    = (int*)   alloc((size_t)(G + 1) * 4);
  ushort* wnT     = (ushort*)alloc(128 * 128 * 2);
  ushort* weT     = (ushort*)alloc(128 * 32 * 2);
  ushort* cweT    = (ushort*)alloc(128 * 160 * 2);
  ushort* owT     = (ushort*)alloc(128 * 128 * 2);
  float*  cbe     = (float*) alloc(128 * 4);
  ushort* efb     = (ushort*)alloc((size_t)E * 32 * 2);    // bf16 edge features
  if ((size_t)(p - (char*)d_ws) > ws_size) efb = nullptr;  // fallback: read f32 ef in conv
  ushort* ract    = cur;  // alias: cur dead after final segsum
  (void)n_in;

  zero_ints<<<(N + 255) / 256, 256, 0, stream>>>(counts, N);
  prep_weights<<<225, 256, 0, stream>>>(wn, we, cw, ow, cb, be, wnT, weT, cweT, owT, cbe);
  count_dst<<<1024, 256, 0, stream>>>(edst, counts, E);
  scan_offsets<<<1, 1024, 0, stream>>>(counts, off, cursor, N);
  fill_csr<<<1024, 256, 0, stream>>>(edst, cursor, eids, E);

  node_linear<<<(N + 63) / 64, 256, 0, stream>>>(node_feat, wnT, bn, ni, N);
  edge_init<<<E / 64, 256, 0, stream>>>(edge_feat, weT, be, esrc, ni, cur, efb, E);

  for (int it = 0; it < 3; ++it) {
    segsum<<<(N + 3) / 4, 256, 0, stream>>>(cur, off, eids, ni, N);
    conv_step<<<E / 64, 256, 0, stream>>>(cur, ni, efb, edge_feat, cweT, cbe, esrc, E);
  }
  segsum<<<(N + 3) / 4, 256, 0, stream>>>(cur, off, eids, ni, N);
  out_linear<<<(N + 63) / 64, 256, 0, stream>>>(ni, owT, ob, ract, N);
  graph_offsets<<<(N + 256) / 256, 256, 0, stream>>>(gids, goff, N, G);
  graph_pool<<<G, 256, 0, stream>>>(ract, goff, out, G);
}

// Round 7
// 1112.384 us; speedup vs baseline: 1.0681x; 1.0362x over previous
//
#include <hip/hip_runtime.h>
#include <hip/hip_bf16.h>
#include <stdint.h>

typedef __attribute__((ext_vector_type(8))) short short8;
typedef __attribute__((ext_vector_type(4))) float f32x4;

#if defined(__has_builtin)
#if __has_builtin(__builtin_amdgcn_cvt_pk_bf16_f32)
#define HAVE_PK_BF16 1
#endif
#endif

__device__ __forceinline__ float b2f(ushort u) {
  union { uint32_t i; float f; } v; v.i = ((uint32_t)u) << 16; return v.f;
}
__device__ __forceinline__ ushort f2b_sw(float f) {
  union { float f; uint32_t i; } v; v.f = f;
  uint32_t x = v.i;
  uint32_t r = x + 0x7FFFu + ((x >> 16) & 1u);
  return (ushort)(r >> 16);
}
__device__ __forceinline__ uint pk2(float lo, float hi) {
#ifdef HAVE_PK_BF16
  auto r = __builtin_amdgcn_cvt_pk_bf16_f32(lo, hi);
  union { decltype(r) v; uint u; } c; c.v = r; return c.u;
#else
  return (uint)f2b_sw(lo) | ((uint)f2b_sw(hi) << 16);
#endif
}
__device__ __forceinline__ ushort f2b(float f) {
#ifdef HAVE_PK_BF16
  return (ushort)(pk2(f, 0.f) & 0xFFFFu);
#else
  return f2b_sw(f);
#endif
}
__device__ __forceinline__ float lo2f(uint v) { return b2f((ushort)(v & 0xFFFFu)); }
__device__ __forceinline__ float hi2f(uint v) { return b2f((ushort)(v >> 16)); }

__device__ __forceinline__ uint4 pkf8(float4 a, float4 b) {
  uint4 o;
  o.x = pk2(a.x, a.y); o.y = pk2(a.z, a.w);
  o.z = pk2(b.x, b.y); o.w = pk2(b.z, b.w);
  return o;
}
__device__ __forceinline__ uint sub2(uint a, uint b) {
  return pk2(lo2f(a) - lo2f(b), hi2f(a) - hi2f(b));
}
__device__ __forceinline__ uint4 sub8(uint4 a, uint4 b) {
  uint4 o; o.x = sub2(a.x,b.x); o.y = sub2(a.y,b.y); o.z = sub2(a.z,b.z); o.w = sub2(a.w,b.w); return o;
}
__device__ __forceinline__ uint addrelu2(uint a, uint b) {
  return pk2(fmaxf(lo2f(a) + lo2f(b), 0.f), fmaxf(hi2f(a) + hi2f(b), 0.f));
}
__device__ __forceinline__ uint4 addrelu8(uint4 a, uint4 b) {
  uint4 o; o.x = addrelu2(a.x,b.x); o.y = addrelu2(a.y,b.y);
  o.z = addrelu2(a.z,b.z); o.w = addrelu2(a.w,b.w); return o;
}
__device__ __forceinline__ uint relu2(uint v) {
  uint lo = (v & 0x8000u) ? 0u : (v & 0xFFFFu);
  uint hi = (v & 0x80000000u) ? 0u : (v & 0xFFFF0000u);
  return lo | hi;
}
__device__ __forceinline__ uint4 relu8(uint4 v) {
  uint4 o; o.x = relu2(v.x); o.y = relu2(v.y); o.z = relu2(v.z); o.w = relu2(v.w); return o;
}
__device__ __forceinline__ void acc8(const uint4& v, float4& a, float4& b) {
  a.x += lo2f(v.x); a.y += hi2f(v.x); a.z += lo2f(v.y); a.w += hi2f(v.y);
  b.x += lo2f(v.z); b.y += hi2f(v.z); b.z += lo2f(v.w); b.w += hi2f(v.w);
}

__global__ void zero_ints(int* __restrict__ p, int n) {
  int i = blockIdx.x * blockDim.x + threadIdx.x;
  if (i < n) p[i] = 0;
}

// ---------- weight prep ----------
__global__ void prep_weights(const float* __restrict__ wn, const float* __restrict__ we,
                             const float* __restrict__ cw, const float* __restrict__ ow,
                             const float* __restrict__ cb, const float* __restrict__ be,
                             ushort* __restrict__ wnT, ushort* __restrict__ weT,
                             ushort* __restrict__ cweT, ushort* __restrict__ owT,
                             float* __restrict__ cbe) {
  int i = blockIdx.x * blockDim.x + threadIdx.x;
  if (i < 16384) {
    int n = i >> 7, k = i & 127; wnT[n*128+k] = f2b(wn[k*128+n]);
  } else if (i < 32768) {
    int j = i - 16384; int n = j >> 7, k = j & 127; owT[n*128+k] = f2b(ow[k*128+n]);
  } else if (i < 53248) {
    int j = i - 32768;           // 128*160 entries
    int n = j / 160, k = j % 160;
    cweT[n*160+k] = (k < 128) ? f2b(cw[k*128+n]) : f2b(we[(k-128)*128+n]);
  } else if (i < 57344) {
    int j = i - 53248; int n = j >> 5, k = j & 31; weT[n*32+k] = f2b(we[k*128+n]);
  } else if (i < 57472) {
    int j = i - 57344; cbe[j] = cb[j] + be[j];
  }
}

// ---------- CSR build ----------
__global__ void count_dst(const int* __restrict__ dst, int* __restrict__ counts, int E) {
  for (int i = blockIdx.x * blockDim.x + threadIdx.x; i < E; i += gridDim.x * blockDim.x)
    atomicAdd(&counts[dst[i]], 1);
}
__global__ __launch_bounds__(1024) void scan_offsets(
    const int* __restrict__ counts, int* __restrict__ off,
    int* __restrict__ cursor, int N) {
  __shared__ int part[1024];
  int t = threadIdx.x;
  int chunk = (N + 1023) >> 10;
  int lo = t * chunk, hi = min(lo + chunk, N);
  int s = 0;
  for (int i = lo; i < hi; ++i) s += counts[i];
  part[t] = s;
  __syncthreads();
  for (int d = 1; d < 1024; d <<= 1) {
    int v = (t >= d) ? part[t - d] : 0;
    __syncthreads();
    part[t] += v;
    __syncthreads();
  }
  int run = (t > 0) ? part[t - 1] : 0;
  for (int i = lo; i < hi; ++i) {
    off[i] = run; cursor[i] = run; run += counts[i];
  }
  if (t == 1023) off[N] = part[1023];
}
__global__ void fill_csr(const int* __restrict__ dst, int* __restrict__ cursor,
                         int* __restrict__ eids, int E) {
  for (int i = blockIdx.x * blockDim.x + threadIdx.x; i < E; i += gridDim.x * blockDim.x) {
    int p = atomicAdd(&cursor[dst[i]], 1);
    eids[p] = i;
  }
}

// ---------- ni[:,128:256) = bf16(node_feat @ Wn + bn) ----------
__global__ __launch_bounds__(256) void node_linear(
    const float* __restrict__ nf, const ushort* __restrict__ wnT,
    const float* __restrict__ bn, ushort* __restrict__ ni, int N) {
  __shared__ ushort Als[64][136];
  __shared__ ushort Bls[128][136];
  int tid = threadIdx.x;
  int n0 = blockIdx.x * 64;
  {
    int row = tid >> 1, h = tid & 1;
    const uint4* gp = (const uint4*)(wnT + row*128 + h*64);
    uint4* lp = (uint4*)&Bls[row][h*64];
    #pragma unroll
    for (int i = 0; i < 8; ++i) lp[i] = gp[i];
  }
  {
    int r = tid >> 2, q = tid & 3;
    int n = n0 + r;
    uint4* lp = (uint4*)&Als[r][q*32];
    if (n < N) {
      const float4* fp = (const float4*)(nf + (size_t)n*128 + q*32);
      #pragma unroll
      for (int i = 0; i < 4; ++i) lp[i] = pkf8(fp[2*i], fp[2*i+1]);
    } else {
      uint4 z = {0,0,0,0};
      #pragma unroll
      for (int i = 0; i < 4; ++i) lp[i] = z;
    }
  }
  __syncthreads();
  int l = tid & 63, w = tid >> 6, quad = l >> 4, mr = l & 15;
  f32x4 acc[8];
  #pragma unroll
  for (int nt = 0; nt < 8; ++nt) acc[nt] = (f32x4){0.f,0.f,0.f,0.f};
  #pragma unroll
  for (int kk = 0; kk < 4; ++kk) {
    short8 a = *(const short8*)&Als[w*16 + mr][kk*32 + quad*8];
    #pragma unroll
    for (int nt = 0; nt < 8; ++nt) {
      short8 b = *(const short8*)&Bls[nt*16 + mr][kk*32 + quad*8];
      acc[nt] = __builtin_amdgcn_mfma_f32_16x16x32_bf16(a, b, acc[nt], 0, 0, 0);
    }
  }
  #pragma unroll
  for (int nt = 0; nt < 8; ++nt) {
    int col = nt*16 + mr;
    float bias = bn[col];
    #pragma unroll
    for (int rg = 0; rg < 4; ++rg) {
      int n = n0 + w*16 + quad*4 + rg;
      if (n < N) ni[(size_t)n*256 + 128 + col] = f2b(acc[nt][rg] + bias);
    }
  }
}

// ---------- cur = relu(inl[src] + ef @ We + be); emits efb = bf16(ef) ----------
__global__ __launch_bounds__(256) void edge_init(
    const float* __restrict__ ef, const ushort* __restrict__ weT,
    const float* __restrict__ be, const int* __restrict__ esrc,
    const ushort* __restrict__ ni, ushort* __restrict__ cur,
    ushort* __restrict__ efb, int E) {
  __shared__ ushort Als[64][40];
  __shared__ ushort Cls[64][136];
  int tid = threadIdx.x;
  int e0 = blockIdx.x * 64;
  int l = tid & 63, w = tid >> 6, quad = l >> 4, mr = l & 15;
  int r = tid >> 2, q = tid & 3;

  short8 bfrag[2];
  #pragma unroll
  for (int nt = 0; nt < 2; ++nt)
    bfrag[nt] = *(const short8*)(weT + (size_t)(w*32 + nt*16 + mr)*32 + quad*8);

  int e = e0 + r;
  int s = esrc[e];
  { // stage A (edge_feat f32 -> bf16) + efb emit
    const float4* fp = (const float4*)(ef + (size_t)e*32 + q*8);
    uint4 pk = pkf8(fp[0], fp[1]);
    *(uint4*)&Als[r][q*8] = pk;
    if (efb) *(uint4*)(efb + (size_t)e*32 + q*8) = pk;
  }
  // prefetch epilogue inl row (hidden under MFMA phase)
  uint4 irow[4];
  {
    const uint4* ip = (const uint4*)(ni + (size_t)s*256 + 128 + q*32);
    #pragma unroll
    for (int i = 0; i < 4; ++i) irow[i] = ip[i];
  }
  __syncthreads();

  int col0 = w*32 + mr, col1 = w*32 + 16 + mr;
  float bias0 = be[col0], bias1 = be[col1];
  #pragma unroll
  for (int m = 0; m < 4; ++m) {
    short8 a = *(const short8*)&Als[m*16 + mr][quad*8];
    f32x4 zero = (f32x4){0.f,0.f,0.f,0.f};
    f32x4 acc0 = __builtin_amdgcn_mfma_f32_16x16x32_bf16(a, bfrag[0], zero, 0, 0, 0);
    f32x4 acc1 = __builtin_amdgcn_mfma_f32_16x16x32_bf16(a, bfrag[1], zero, 0, 0, 0);
    #pragma unroll
    for (int rg = 0; rg < 4; ++rg) {
      int row = m*16 + quad*4 + rg;
      Cls[row][col0] = f2b(acc0[rg] + bias0);
      Cls[row][col1] = f2b(acc1[rg] + bias1);
    }
  }
  __syncthreads();

  { // packed epilogue: cur[e] = relu(C + inl_row)
    const uint4* cl = (const uint4*)&Cls[r][q*32];
    uint4* op = (uint4*)(cur + (size_t)e*128 + q*32);
    #pragma unroll
    for (int i = 0; i < 4; ++i) op[i] = addrelu8(cl[i], irow[i]);
  }
}

// ---------- segment-sum v3: uint4/lane (4 rows per instr), 16 rows in flight ----------
__global__ __launch_bounds__(256) void segsum(
    const ushort* __restrict__ cur, const int* __restrict__ off,
    const int* __restrict__ eids, ushort* __restrict__ ni, int N) {
  int w = threadIdx.x >> 6, l = threadIdx.x & 63;
  int n = blockIdx.x * 4 + w;
  if (n >= N) return;
  int c16 = l & 15;     // 16B chunk -> 8 bf16 cols
  int row4 = l >> 4;    // 0..3: which row of the 4-row group
  int beg = off[n], end = off[n + 1];
  float4 sa = {0.f,0.f,0.f,0.f}, sb = {0.f,0.f,0.f,0.f};
  int i = beg;
  for (; i + 16 <= end; i += 16) {           // 16 rows (4 KB) in flight
    uint4 v[4];
    #pragma unroll
    for (int j = 0; j < 4; ++j) {
      int e = eids[i + 4*j + row4];
      v[j] = *(const uint4*)(cur + (size_t)e*128 + c16*8);
    }
    #pragma unroll
    for (int j = 0; j < 4; ++j) acc8(v[j], sa, sb);
  }
  for (; i + 4 <= end; i += 4) {
    int e = eids[i + row4];
    uint4 v = *(const uint4*)(cur + (size_t)e*128 + c16*8);
    acc8(v, sa, sb);
  }
  if (i + row4 < end) {
    int e = eids[i + row4];
    uint4 v = *(const uint4*)(cur + (size_t)e*128 + c16*8);
    acc8(v, sa, sb);
  }
  // reduce the 4 row-groups (lanes differing in bits 4..5)
  #pragma unroll
  for (int d = 16; d <= 32; d <<= 1) {
    sa.x += __shfl_xor(sa.x, d); sa.y += __shfl_xor(sa.y, d);
    sa.z += __shfl_xor(sa.z, d); sa.w += __shfl_xor(sa.w, d);
    sb.x += __shfl_xor(sb.x, d); sb.y += __shfl_xor(sb.y, d);
    sb.z += __shfl_xor(sb.z, d); sb.w += __shfl_xor(sb.w, d);
  }
  if (row4 == 0) {
    uint4 o;
    o.x = pk2(sa.x, sa.y); o.y = pk2(sa.z, sa.w);
    o.z = pk2(sb.x, sb.y); o.w = pk2(sb.z, sb.w);
    *(uint4*)(ni + (size_t)n*256 + c16*8) = o;
  }
}

// ---------- cur = relu([nagg[src]-cur[e^1] | efb] @ [Wc|We]^T + (cb+be) + inl[src]) ----------
__global__ __launch_bounds__(256) void conv_step(
    ushort* __restrict__ cur, const ushort* __restrict__ ni,
    const ushort* __restrict__ efb, const float* __restrict__ ef,
    const ushort* __restrict__ cweT, const float* __restrict__ cbe,
    const int* __restrict__ esrc, int E) {
  __shared__ ushort Als[64][168];   // A: 64x160; C reuses cols [0,128)
  int tid = threadIdx.x;
  int e0 = blockIdx.x * 64;
  int l = tid & 63, w = tid >> 6, quad = l >> 4, mr = l & 15;
  int r = tid >> 2, q = tid & 3;

  short8 bfrag[2][5];
  #pragma unroll
  for (int nt = 0; nt < 2; ++nt) {
    const ushort* bp = cweT + (size_t)(w*32 + nt*16 + mr) * 160;
    #pragma unroll
    for (int kk = 0; kk < 5; ++kk)
      bfrag[nt][kk] = *(const short8*)(bp + kk*32 + quad*8);
  }

  int e = e0 + r;
  int s = esrc[e];
  { // stage A: cols[0,128) = nagg[src] - cur[e^1]; cols[128,160) = bf16 edge feat
    const uint4* cp = (const uint4*)(cur + (size_t)(e ^ 1)*128 + q*32);
    const uint4* np = (const uint4*)(ni + (size_t)s*256 + q*32);
    uint4* lp = (uint4*)&Als[r][q*32];
    #pragma unroll
    for (int i = 0; i < 4; ++i) lp[i] = sub8(np[i], cp[i]);
    if (efb) {
      *(uint4*)&Als[r][128 + q*8] = *(const uint4*)(efb + (size_t)e*32 + q*8);
    } else {
      const float4* fp = (const float4*)(ef + (size_t)e*32 + q*8);
      *(uint4*)&Als[r][128 + q*8] = pkf8(fp[0], fp[1]);
    }
  }
  // prefetch epilogue inl row (adjacent half of the same ni row)
  uint4 irow[4];
  {
    const uint4* ip = (const uint4*)(ni + (size_t)s*256 + 128 + q*32);
    #pragma unroll
    for (int i = 0; i < 4; ++i) irow[i] = ip[i];
  }
  __syncthreads();

  int col0 = w*32 + mr, col1 = w*32 + 16 + mr;
  float bias0 = cbe[col0], bias1 = cbe[col1];
  f32x4 acc0[4], acc1[4];
  #pragma unroll
  for (int m = 0; m < 4; ++m) {
    acc0[m] = (f32x4){0.f,0.f,0.f,0.f};
    acc1[m] = (f32x4){0.f,0.f,0.f,0.f};
    #pragma unroll
    for (int kk = 0; kk < 5; ++kk) {
      short8 a = *(const short8*)&Als[m*16 + mr][kk*32 + quad*8];
      acc0[m] = __builtin_amdgcn_mfma_f32_16x16x32_bf16(a, bfrag[0][kk], acc0[m], 0, 0, 0);
      acc1[m] = __builtin_amdgcn_mfma_f32_16x16x32_bf16(a, bfrag[1][kk], acc1[m], 0, 0, 0);
    }
  }
  __syncthreads();  // all A reads done -> overwrite Als with C

  #pragma unroll
  for (int m = 0; m < 4; ++m) {
    #pragma unroll
    for (int rg = 0; rg < 4; ++rg) {
      int row = m*16 + quad*4 + rg;
      Als[row][col0] = f2b(acc0[m][rg] + bias0);
      Als[row][col1] = f2b(acc1[m][rg] + bias1);
    }
  }
  __syncthreads();

  { // packed epilogue: cur[e] = relu(C + inl_row)  (inl already in regs)
    const uint4* cl = (const uint4*)&Als[r][q*32];
    uint4* op = (uint4*)(cur + (size_t)e*128 + q*32);
    #pragma unroll
    for (int i = 0; i < 4; ++i) op[i] = addrelu8(cl[i], irow[i]);
  }
}

// ---------- ract(bf16) = relu(relu(nagg) @ Wo + ob) ----------
__global__ __launch_bounds__(256) void out_linear(
    const ushort* __restrict__ ni, const ushort* __restrict__ owT,
    const float* __restrict__ ob, ushort* __restrict__ ract, int N) {
  __shared__ ushort Als[64][136];
  __shared__ ushort Bls[128][136];
  int tid = threadIdx.x;
  int n0 = blockIdx.x * 64;
  {
    int row = tid >> 1, h = tid & 1;
    const uint4* gp = (const uint4*)(owT + row*128 + h*64);
    uint4* lp = (uint4*)&Bls[row][h*64];
    #pragma unroll
    for (int i = 0; i < 8; ++i) lp[i] = gp[i];
  }
  {
    int r = tid >> 2, q = tid & 3;
    int n = n0 + r;
    uint4* lp = (uint4*)&Als[r][q*32];
    if (n < N) {
      const uint4* gp = (const uint4*)(ni + (size_t)n*256 + q*32);
      #pragma unroll
      for (int i = 0; i < 4; ++i) lp[i] = relu8(gp[i]);
    } else {
      uint4 z = {0,0,0,0};
      #pragma unroll
      for (int i = 0; i < 4; ++i) lp[i] = z;
    }
  }
  __syncthreads();
  int l = tid & 63, w = tid >> 6, quad = l >> 4, mr = l & 15;
  f32x4 acc[8];
  #pragma unroll
  for (int nt = 0; nt < 8; ++nt) acc[nt] = (f32x4){0.f,0.f,0.f,0.f};
  #pragma unroll
  for (int kk = 0; kk < 4; ++kk) {
    short8 a = *(const short8*)&Als[w*16 + mr][kk*32 + quad*8];
    #pragma unroll
    for (int nt = 0; nt < 8; ++nt) {
      short8 b = *(const short8*)&Bls[nt*16 + mr][kk*32 + quad*8];
      acc[nt] = __builtin_amdgcn_mfma_f32_16x16x32_bf16(a, b, acc[nt], 0, 0, 0);
    }
  }
  #pragma unroll
  for (int nt = 0; nt < 8; ++nt) {
    int col = nt*16 + mr;
    float bias = ob[col];
    #pragma unroll
    for (int rg = 0; rg < 4; ++rg) {
      int n = n0 + w*16 + quad*4 + rg;
      if (n < N) ract[(size_t)n*128 + col] = f2b(fmaxf(acc[nt][rg] + bias, 0.f));
    }
  }
}

// ---------- per-graph node ranges (graph_ids is sorted), parallel ----------
__global__ void graph_offsets(const int* __restrict__ gids, int* __restrict__ goff,
                              int N, int G) {
  int i = blockIdx.x * blockDim.x + threadIdx.x;
  if (i > N) return;
  int pg = (i == 0) ? -1 : gids[i - 1];
  int cg = (i == N) ? G : gids[i];
  for (int g = pg + 1; g <= cg; ++g) goff[g] = i;
}

// ---------- pool nodes per graph (bf16 in, f32 out) ----------
__global__ __launch_bounds__(256) void graph_pool(
    const ushort* __restrict__ ract, const int* __restrict__ goff,
    float* __restrict__ out, int G) {
  __shared__ float red0[256];
  __shared__ float red1[256];
  int g = blockIdx.x;
  int t = threadIdx.x;
  int c2 = t & 63, rp = t >> 6;
  int beg = goff[g], end = goff[g + 1];
  float s0 = 0.f, s1 = 0.f;
  for (int n = beg + rp; n < end; n += 4) {
    uint v = *(const uint*)(ract + (size_t)n*128 + 2*c2);
    s0 += lo2f(v); s1 += hi2f(v);
  }
  red0[t] = s0; red1[t] = s1;
  __syncthreads();
  if (rp == 0) {
    float v0 = red0[c2] + red0[c2 + 64] + red0[c2 + 128] + red0[c2 + 192];
    float v1 = red1[c2] + red1[c2 + 64] + red1[c2 + 128] + red1[c2 + 192];
    float2 o; o.x = fmaxf(v0, 0.f); o.y = fmaxf(v1, 0.f);
    *(float2*)(out + (size_t)g*128 + 2*c2) = o;
  }
}

extern "C" void kernel_launch(void* const* d_in, const int* in_sizes, int n_in,
                              void* d_out, int out_size, void* d_ws, size_t ws_size,
                              hipStream_t stream) {
  const float* node_feat = (const float*)d_in[0];
  const float* edge_feat = (const float*)d_in[1];
  const float* wn = (const float*)d_in[2];
  const float* bn = (const float*)d_in[3];
  const float* we = (const float*)d_in[4];
  const float* be = (const float*)d_in[5];
  const float* cw = (const float*)d_in[6];
  const float* cb = (const float*)d_in[7];
  const float* ow = (const float*)d_in[8];
  const float* ob = (const float*)d_in[9];
  const int* esrc = (const int*)d_in[10];
  const int* edst = (const int*)d_in[11];
  const int* gids = (const int*)d_in[12];
  int N = in_sizes[0] / 128;
  int E = in_sizes[10];
  int G = out_size / 128;
  float* out = (float*)d_out;

  char* p = (char*)d_ws;
  auto alloc = [&](size_t bytes) {
    char* r = p;
    p += (bytes + 255) & ~(size_t)255;
    return r;
  };
  // ws: cur 204.8 + ni 25.6 + eids 3.2 + ints ~0.6 + weights ~0.12 + efb 51.2 ~= 286 MB
  ushort* cur     = (ushort*)alloc((size_t)E * 128 * 2);
  ushort* ni      = (ushort*)alloc((size_t)N * 256 * 2);   // [nagg | inl] interleaved
  int*    eids    = (int*)   alloc((size_t)E * 4);
  int*    counts  = (int*)   alloc((size_t)N * 4);
  int*    off     = (int*)   alloc((size_t)(N + 1) * 4);
  int*    cursor  = (int*)   alloc((size_t)N * 4);
  int*    goff    = (int*)   alloc((size_t)(G + 1) * 4);
  ushort* wnT     = (ushort*)alloc(128 * 128 * 2);
  ushort* weT     = (ushort*)alloc(128 * 32 * 2);
  ushort* cweT    = (ushort*)alloc(128 * 160 * 2);
  ushort* owT     = (ushort*)alloc(128 * 128 * 2);
  float*  cbe     = (float*) alloc(128 * 4);
  ushort* efb     = (ushort*)alloc((size_t)E * 32 * 2);    // bf16 edge features
  if ((size_t)(p - (char*)d_ws) > ws_size) efb = nullptr;  // fallback: read f32 ef in conv
  ushort* ract    = cur;  // alias: cur dead after final segsum
  (void)n_in;

  zero_ints<<<(N + 255) / 256, 256, 0, stream>>>(counts, N);
  prep_weights<<<225, 256, 0, stream>>>(wn, we, cw, ow, cb, be, wnT, weT, cweT, owT, cbe);
  count_dst<<<2048, 256, 0, stream>>>(edst, counts, E);
  scan_offsets<<<1, 1024, 0, stream>>>(counts, off, cursor, N);
  fill_csr<<<2048, 256, 0, stream>>>(edst, cursor, eids, E);

  node_linear<<<(N + 63) / 64, 256, 0, stream>>>(node_feat, wnT, bn, ni, N);
  edge_init<<<E / 64, 256, 0, stream>>>(edge_feat, weT, be, esrc, ni, cur, efb, E);

  for (int it = 0; it < 3; ++it) {
    segsum<<<(N + 3) / 4, 256, 0, stream>>>(cur, off, eids, ni, N);
    conv_step<<<E / 64, 256, 0, stream>>>(cur, ni, efb, edge_feat, cweT, cbe, esrc, E);
  }
  segsum<<<(N + 3) / 4, 256, 0, stream>>>(cur, off, eids, ni, N);
  out_linear<<<(N + 63) / 64, 256, 0, stream>>>(ni, owT, ob, ract, N);
  graph_offsets<<<(N + 256) / 256, 256, 0, stream>>>(gids, goff, N, G);
  graph_pool<<<G, 256, 0, stream>>>(ract, goff, out, G);
}